// Round 8
// baseline (690.228 us; speedup 1.0000x reference)
//
#include <hip/hip_runtime.h>
#include <stdint.h>

namespace {
constexpr int kNodes = 50000;
constexpr int kEdges = 800000;
constexpr int kHid   = 128;
constexpr int kCap   = 64;                          // ELL row capacity (λ=16)
constexpr int kBlocks32 = (kNodes + 31) / 32;       // 1563 (32-node tiles)
constexpr int kFillBlocks = kEdges / 256;           // 3125
constexpr int kPackBlocks = 448;

// workspace layout (bytes) — ROUND-16: y/msg deleted (S-path), h1 double-buffer
constexpr size_t oCounts = 0;                       // 200704 (cnt, memset region)
constexpr size_t oBpack  = 200704;                  // 655360
constexpr size_t oEll    = 856064;                  // 50000*64*4 = 12800000
constexpr size_t oH1     = 13656064;                // 50000*128*4 = 25600000
constexpr size_t kWsNeeded = oH1 + 25600000;        // 39,256,064

// Bpack sub-offsets (bytes relative to oBpack)
// Khi/Klo/Rhi/Rlo unchanged (r3/r14-verified gru tables, swz_pi-permuted K rows)
// Whi/Wlo REPACKED for the S-path: B2[kk=(t*128+k)][c], K=512, N=128.
constexpr size_t bKhi = 0,      bKlo = 98304,  bRhi = 196608,
                 bRlo = 294912, bWhi = 393216, bWlo = 524288;
}

typedef __attribute__((ext_vector_type(8))) short short8;
typedef __attribute__((ext_vector_type(4))) float f32x4;

union ABFrag { short8 v; uint16_t u[8]; uint4 q; };

__device__ __forceinline__ uint16_t f2bf(float x) {
  uint32_t u = __float_as_uint(x);
  return (uint16_t)((u + 0x7FFFu + ((u >> 16) & 1u)) >> 16);
}
__device__ __forceinline__ float bf2f(uint16_t h) {
  return __uint_as_float(((uint32_t)h) << 16);
}

__device__ __forceinline__ float fast_rcp(float x) {
#if __has_builtin(__builtin_amdgcn_rcpf)
  return __builtin_amdgcn_rcpf(x);
#else
  return 1.f / x;
#endif
}
__device__ __forceinline__ float fast_exp2(float x) {
#if __has_builtin(__builtin_amdgcn_exp2f)
  return __builtin_amdgcn_exp2f(x);
#else
  return exp2f(x);
#endif
}
__device__ __forceinline__ float sigf(float x) {
  return fast_rcp(1.f + fast_exp2(-1.4426950408889634f * x));
}
__device__ __forceinline__ float tanh_fast(float x) {
  x = fminf(fmaxf(x, -10.f), 10.f);
  const float t = fast_exp2(2.8853900817779268f * x);  // e^(2x)
  return (t - 1.f) * fast_rcp(t + 1.f);
}

// msg k-position swizzle (r3-verified): position p holds original col pi(p).
__device__ __forceinline__ int swz_pi(int p) {
  return (p & 64) | ((p & 3) << 4) | ((p >> 2) & 15);
}

__device__ __forceinline__ void split8(const float* p, ABFrag& hi, ABFrag& lo) {
  const float4 a0 = *(const float4*)p;
  const float4 a1 = *(const float4*)(p + 4);
  const float v[8] = {a0.x, a0.y, a0.z, a0.w, a1.x, a1.y, a1.z, a1.w};
#pragma unroll
  for (int j = 0; j < 8; ++j) {
    const uint16_t t = f2bf(v[j]);
    hi.u[j] = t; lo.u[j] = f2bf(v[j] - bf2f(t));
  }
}
__device__ __forceinline__ void conv8(const float* p, ABFrag& hi) {
  const float4 a0 = *(const float4*)p;
  const float4 a1 = *(const float4*)(p + 4);
  const float v[8] = {a0.x, a0.y, a0.z, a0.w, a1.x, a1.y, a1.z, a1.w};
#pragma unroll
  for (int j = 0; j < 8; ++j) hi.u[j] = f2bf(v[j]);
}

// ---------------- FUSED prep: ELL fill + B-pack (independent outputs) --------
__global__ __launch_bounds__(256) void pack_fill_kernel(
    const int* __restrict__ edges, int* __restrict__ cnt,
    unsigned* __restrict__ ell,
    const float* __restrict__ K, const float* __restrict__ R,
    const float* __restrict__ W, uint16_t* __restrict__ bp) {
  if (blockIdx.x < kFillBlocks) {
    const int e = blockIdx.x * 256 + threadIdx.x;
    if (e < kEdges) {
      const int et  = edges[e * 3 + 0];
      const int src = edges[e * 3 + 1];
      const int tgt = edges[e * 3 + 2];
      const int pos = atomicAdd(&cnt[tgt], 1);
      if (pos < kCap) ell[(size_t)tgt * kCap + pos] = (unsigned)(src * 4 + et);
    }
    return;
  }
  // ---- pack path (448 blocks)
  const int idx = (blockIdx.x - kFillBlocks) * 256 + threadIdx.x;
  uint16_t* khi = bp + bKhi / 2;
  uint16_t* klo = bp + bKlo / 2;
  uint16_t* rhi = bp + bRhi / 2;
  uint16_t* rlo = bp + bRlo / 2;
  uint16_t* whi = bp + bWhi / 2;
  uint16_t* wlo = bp + bWlo / 2;
  if (idx < 128 * 384) {
    // K/R gru tables: UNCHANGED (r3/r14-verified), K rows permuted by swz_pi
    const int k = idx / 384, c = idx % 384;
    const int ksrc = swz_pi(k);
    const int kt = k >> 5, quad = (k >> 3) & 3, j = k & 7;
    const int nt = c >> 4, ln = (c & 15) | (quad << 4);
    const size_t o = ((size_t)(kt * 24 + nt) * 64 + ln) * 8 + j;
    const float kv = K[ksrc * 384 + c];
    const float rv = R[k * 384 + c];
    const uint16_t kh = f2bf(kv), rh = f2bf(rv);
    khi[o] = kh; klo[o] = f2bf(kv - bf2f(kh));
    rhi[o] = rh; rlo[o] = f2bf(rv - bf2f(rh));
  } else if (idx < 128 * 384 + 128 * 512) {
    // W2: B for msg = S @ W2, K index kk = t*128+k (512), col c (128)
    const int i2 = idx - 128 * 384;      // 0..65535
    const int kk = i2 >> 7;              // 0..511
    const int c  = i2 & 127;             // 0..127
    const int t = kk >> 7, k = kk & 127;
    const float wv = W[((size_t)t * 128 + k) * 128 + c];
    const int kt2 = kk >> 5, quad = (kk >> 3) & 3, j = kk & 7;
    const int nt = c >> 4, ln = (c & 15) | (quad << 4);
    const size_t o = ((size_t)(kt2 * 8 + nt) * 64 + ln) * 8 + j;
    const uint16_t wh = f2bf(wv);
    whi[o] = wh; wlo[o] = f2bf(wv - bf2f(wh));
  }
}

// ---------------- FUSED gather-S + (S@W2 + bias) + GRU (ROUND-16) ------------
// Per 32-node block (256 thr, 4 waves):
//  P1: per-type fp32 sums S_t[v] = Σ h[src] into LDS S[32][516] (+pad, 2-way
//      banks), type counts into D. (message_fb structure, 8-deep load ILP.)
//  P2: msg = S @ W2 + Σ_t D_t·TB_t. M=32,N=128,K=512, 3-term bf16 split,
//      A from LDS (16B-aligned, 2-way bank), B = repacked Whi/Wlo (L2-hot).
//      Epilogue writes bf16 msg into the r3-VERIFIED swizzled frag layout
//      (msgT, overlaid on S after a barrier) so P3 reads drop into A-frags.
//  P3: r14 gru body verbatim (mh from LDS msgT instead of global msg16).
// Eliminates per step vs r7: y write (51MB), y gather-fetch (~110MB), msg
// write+read (25.6MB), 2 dispatches. NO in-place hazard: hin != hout always
// (step1 states->h1, step2 h1->out), so cross-block random h reads are safe.
__global__ __launch_bounds__(256, 2) void fused_msg_gru(
    const float* __restrict__ hin,      // [N][128] (states or h1)
    const unsigned* __restrict__ ell,
    const int* __restrict__ counts,
    const uint16_t* __restrict__ bp,
    const float* __restrict__ TB,       // [4][128]
    const float* __restrict__ gb,       // [2][384]
    float* __restrict__ hout) {         // [N][128] (h1 or out; != hin)
  __shared__ __align__(16) float S[32 * 516];
  __shared__ int D[32][4];
  const int tid = threadIdx.x;
  const int node0 = blockIdx.x * 32;

  // ---- phase 1: gather per-type h sums + counts
  {
    const int g = tid >> 7;            // 2 groups x 128 threads
    const int j = tid & 127;
    for (int i = 0; i < 16; ++i) {
      const int nl = g * 16 + i;
      const int v = node0 + nl;
      float a0 = 0.f, a1 = 0.f, a2 = 0.f, a3 = 0.f;
      int d0 = 0, d1 = 0, d2 = 0, d3 = 0;
      if (v < kNodes) {
        const int cnt = min(counts[v], kCap);
        const unsigned* __restrict__ row = ell + (size_t)v * kCap;
        int e = 0;
        for (; e + 8 <= cnt; e += 8) {
          unsigned p[8]; float val[8];
#pragma unroll
          for (int q = 0; q < 8; ++q) p[q] = row[e + q];
#pragma unroll
          for (int q = 0; q < 8; ++q)
            val[q] = hin[(size_t)(p[q] >> 2) * kHid + j];
#pragma unroll
          for (int q = 0; q < 8; ++q) {
            const int t = (int)(p[q] & 3u);
            a0 += (t == 0) ? val[q] : 0.f; a1 += (t == 1) ? val[q] : 0.f;
            a2 += (t == 2) ? val[q] : 0.f; a3 += (t == 3) ? val[q] : 0.f;
            d0 += (t == 0); d1 += (t == 1); d2 += (t == 2); d3 += (t == 3);
          }
        }
        for (; e < cnt; ++e) {
          const unsigned p = row[e];
          const float val = hin[(size_t)(p >> 2) * kHid + j];
          const int t = (int)(p & 3u);
          a0 += (t == 0) ? val : 0.f; a1 += (t == 1) ? val : 0.f;
          a2 += (t == 2) ? val : 0.f; a3 += (t == 3) ? val : 0.f;
          d0 += (t == 0); d1 += (t == 1); d2 += (t == 2); d3 += (t == 3);
        }
      }
      float* Sn = &S[nl * 516];
      Sn[j] = a0; Sn[128 + j] = a1; Sn[256 + j] = a2; Sn[384 + j] = a3;
      if (j == 0) { D[nl][0] = d0; D[nl][1] = d1; D[nl][2] = d2; D[nl][3] = d3; }
    }
  }
  __syncthreads();

  // ---- phase 2: msg = S @ W2 (+ D·TB)
  const int w = tid >> 6;
  const int lane = tid & 63;
  const int col16 = lane & 15, quad = lane >> 4;
  const uint4* __restrict__ Whi = (const uint4*)(bp + bWhi / 2);
  const uint4* __restrict__ Wlo = (const uint4*)(bp + bWlo / 2);

  f32x4 acc[2][2];                     // [lnt][m]
#pragma unroll
  for (int i = 0; i < 2; ++i)
#pragma unroll
    for (int m = 0; m < 2; ++m) acc[i][m] = (f32x4){0.f, 0.f, 0.f, 0.f};

  for (int kt2 = 0; kt2 < 16; ++kt2) {
    ABFrag ah[2], al[2];
#pragma unroll
    for (int m = 0; m < 2; ++m)
      split8(&S[(size_t)(col16 + m * 16) * 516 + kt2 * 32 + quad * 8],
             ah[m], al[m]);
    ABFrag bh[2], bl[2];
#pragma unroll
    for (int lnt = 0; lnt < 2; ++lnt) {
      const size_t o = (size_t)(kt2 * 8 + w * 2 + lnt) * 64 + lane;
      bh[lnt].q = Whi[o]; bl[lnt].q = Wlo[o];
    }
#pragma unroll
    for (int lnt = 0; lnt < 2; ++lnt)
#pragma unroll
      for (int m = 0; m < 2; ++m) {
        f32x4 c = acc[lnt][m];
        c = __builtin_amdgcn_mfma_f32_16x16x32_bf16(ah[m].v, bh[lnt].v, c, 0, 0, 0);
        c = __builtin_amdgcn_mfma_f32_16x16x32_bf16(ah[m].v, bl[lnt].v, c, 0, 0, 0);
        c = __builtin_amdgcn_mfma_f32_16x16x32_bf16(al[m].v, bh[lnt].v, c, 0, 0, 0);
        acc[lnt][m] = c;
      }
  }
  __syncthreads();   // all waves done reading S before msgT overlay

  // epilogue: + bias, f2bf, scatter into swizzled frag-order msgT (on S).
  // col c -> k-position p with pi(p)=c (r3-verified convention, matches the
  // swz_pi-permuted Khi/Klo gru tables): p = (c>>6)*64 + (c&15)*4 + ((c>>4)&3)
  uint16_t* msgT16 = (uint16_t*)S;
#pragma unroll
  for (int lnt = 0; lnt < 2; ++lnt) {
    const int c = (w * 2 + lnt) * 16 + col16;
    const float tb0 = TB[c], tb1 = TB[128 + c], tb2 = TB[256 + c],
                tb3 = TB[384 + c];
    const int p = ((c >> 6) << 6) | (col16 << 2) | ((c >> 4) & 3);
    const int kt = p >> 5, hi3 = (p >> 3) & 3, jq = p & 7;
#pragma unroll
    for (int m = 0; m < 2; ++m)
#pragma unroll
      for (int r = 0; r < 4; ++r) {
        const int n16 = quad * 4 + r;
        const int nl = m * 16 + n16;
        const float bias = (float)D[nl][0] * tb0 + (float)D[nl][1] * tb1 +
                           (float)D[nl][2] * tb2 + (float)D[nl][3] * tb3;
        msgT16[((m * 4 + kt) * 64 + hi3 * 16 + n16) * 8 + jq] =
            f2bf(acc[lnt][m][r] + bias);
      }
  }
  __syncthreads();

  // ---- phase 3: gru (r14 body; mh from LDS msgT frags)
  const uint4* __restrict__ msgQ = (const uint4*)msgT16;
  const uint4* __restrict__ Khi = (const uint4*)(bp + bKhi / 2);
  const uint4* __restrict__ Klo = (const uint4*)(bp + bKlo / 2);
  const uint4* __restrict__ Rhi = (const uint4*)(bp + bRhi / 2);
  const uint4* __restrict__ Rlo = (const uint4*)(bp + bRlo / 2);

  bool mok[2];
#pragma unroll
  for (int m = 0; m < 2; ++m) mok[m] = (node0 + m * 16) < kNodes;

  f32x4 aZ[2][2], aR[2][2], aX[2][2], aH[2][2];  // [lnt][m-tile]
#pragma unroll
  for (int i = 0; i < 2; ++i)
#pragma unroll
    for (int m = 0; m < 2; ++m) {
      aZ[i][m] = (f32x4){0.f, 0.f, 0.f, 0.f};
      aR[i][m] = aZ[i][m]; aX[i][m] = aZ[i][m]; aH[i][m] = aZ[i][m];
    }

  const float* hrow = hin + (size_t)(node0 + col16) * kHid + quad * 8;

#pragma unroll
  for (int kt = 0; kt < 4; ++kt) {
    float4 hraw[2][2];
#pragma unroll
    for (int m = 0; m < 2; ++m) {
      if (mok[m]) {
        hraw[m][0] = *(const float4*)(hrow + (size_t)m * 16 * kHid + kt * 32);
        hraw[m][1] = *(const float4*)(hrow + (size_t)m * 16 * kHid + kt * 32 + 4);
      } else {
        hraw[m][0] = make_float4(0.f, 0.f, 0.f, 0.f);
        hraw[m][1] = hraw[m][0];
      }
    }
    ABFrag BZ[2][4], BR[2][4], BH[2][4];  // [lnt][Khi,Klo,Rhi,Rlo]
#pragma unroll
    for (int lnt = 0; lnt < 2; ++lnt) {
      const int ntc = w * 2 + lnt;
      const size_t oz = (size_t)(kt * 24 + ntc) * 64 + lane;
      const size_t orr = (size_t)(kt * 24 + 8 + ntc) * 64 + lane;
      const size_t oh = (size_t)(kt * 24 + 16 + ntc) * 64 + lane;
      BZ[lnt][0].q = Khi[oz];  BZ[lnt][1].q = Klo[oz];
      BZ[lnt][2].q = Rhi[oz];  BZ[lnt][3].q = Rlo[oz];
      BR[lnt][0].q = Khi[orr]; BR[lnt][1].q = Klo[orr];
      BR[lnt][2].q = Rhi[orr]; BR[lnt][3].q = Rlo[orr];
      BH[lnt][0].q = Khi[oh];  BH[lnt][1].q = Klo[oh];
      BH[lnt][2].q = Rhi[oh];  BH[lnt][3].q = Rlo[oh];
    }
    ABFrag mh[2], hh[2];
#pragma unroll
    for (int m = 0; m < 2; ++m) {
      mh[m].q = msgQ[(m * 4 + kt) * 64 + lane];
      const float vv[8] = {hraw[m][0].x, hraw[m][0].y, hraw[m][0].z, hraw[m][0].w,
                           hraw[m][1].x, hraw[m][1].y, hraw[m][1].z, hraw[m][1].w};
#pragma unroll
      for (int j = 0; j < 8; ++j) hh[m].u[j] = f2bf(vv[j]);
    }
#pragma unroll
    for (int lnt = 0; lnt < 2; ++lnt) {
#pragma unroll
      for (int m = 0; m < 2; ++m) {
        f32x4 z = aZ[lnt][m];
        z = __builtin_amdgcn_mfma_f32_16x16x32_bf16(mh[m].v, BZ[lnt][0].v, z, 0, 0, 0);
        z = __builtin_amdgcn_mfma_f32_16x16x32_bf16(mh[m].v, BZ[lnt][1].v, z, 0, 0, 0);
        z = __builtin_amdgcn_mfma_f32_16x16x32_bf16(hh[m].v, BZ[lnt][2].v, z, 0, 0, 0);
        z = __builtin_amdgcn_mfma_f32_16x16x32_bf16(hh[m].v, BZ[lnt][3].v, z, 0, 0, 0);
        aZ[lnt][m] = z;
        f32x4 r = aR[lnt][m];
        r = __builtin_amdgcn_mfma_f32_16x16x32_bf16(mh[m].v, BR[lnt][0].v, r, 0, 0, 0);
        r = __builtin_amdgcn_mfma_f32_16x16x32_bf16(mh[m].v, BR[lnt][1].v, r, 0, 0, 0);
        r = __builtin_amdgcn_mfma_f32_16x16x32_bf16(hh[m].v, BR[lnt][2].v, r, 0, 0, 0);
        r = __builtin_amdgcn_mfma_f32_16x16x32_bf16(hh[m].v, BR[lnt][3].v, r, 0, 0, 0);
        aR[lnt][m] = r;
        f32x4 x = aX[lnt][m];
        x = __builtin_amdgcn_mfma_f32_16x16x32_bf16(mh[m].v, BH[lnt][0].v, x, 0, 0, 0);
        x = __builtin_amdgcn_mfma_f32_16x16x32_bf16(mh[m].v, BH[lnt][1].v, x, 0, 0, 0);
        aX[lnt][m] = x;
        f32x4 y = aH[lnt][m];
        y = __builtin_amdgcn_mfma_f32_16x16x32_bf16(hh[m].v, BH[lnt][2].v, y, 0, 0, 0);
        y = __builtin_amdgcn_mfma_f32_16x16x32_bf16(hh[m].v, BH[lnt][3].v, y, 0, 0, 0);
        aH[lnt][m] = y;
      }
    }
  }

  // ---- gru epilogue (wave-column-local; hout != hin so no hazard)
#pragma unroll
  for (int lnt = 0; lnt < 2; ++lnt) {
    const int c = (w * 2 + lnt) * 16 + col16;
    const float bz = gb[c] + gb[384 + c];
    const float br = gb[128 + c] + gb[512 + c];
    const float bx = gb[256 + c];
    const float bh = gb[640 + c];
#pragma unroll
    for (int m = 0; m < 2; ++m) {
      if (!mok[m]) continue;
#pragma unroll
      for (int r = 0; r < 4; ++r) {
        const int node = node0 + m * 16 + quad * 4 + r;
        const float hp = hin[(size_t)node * kHid + c];
        const float z = sigf(aZ[lnt][m][r] + bz);
        const float rr = sigf(aR[lnt][m][r] + br);
        const float hh = tanh_fast(aX[lnt][m][r] + bx + rr * (aH[lnt][m][r] + bh));
        hout[(size_t)node * kHid + c] = z * hp + (1.f - z) * hh;
      }
    }
  }
}

extern "C" void kernel_launch(void* const* d_in, const int* in_sizes, int n_in,
                              void* d_out, int out_size, void* d_ws, size_t ws_size,
                              hipStream_t stream) {
  const float* states = (const float*)d_in[0];
  const int*   edges  = (const int*)d_in[1];
  const float* W      = (const float*)d_in[2];
  const float* TB     = (const float*)d_in[3];
  const float* K      = (const float*)d_in[4];
  const float* R      = (const float*)d_in[5];
  const float* gb     = (const float*)d_in[6];
  float* out = (float*)d_out;

  if (ws_size < kWsNeeded) return;

  char* ws = (char*)d_ws;
  int*      counts = (int*)(ws + oCounts);
  uint16_t* bpack  = (uint16_t*)(ws + oBpack);
  unsigned* ell    = (unsigned*)(ws + oEll);
  float*    h1     = (float*)(ws + oH1);

  hipMemsetAsync(counts, 0, 200704, stream);
  // prep: ELL scatter-fill + B-pack in one dispatch (independent outputs)
  pack_fill_kernel<<<kFillBlocks + kPackBlocks, 256, 0, stream>>>(
      edges, counts, ell, K, R, W, bpack);
  // step 1: states -> h1
  fused_msg_gru<<<kBlocks32, 256, 0, stream>>>(states, ell, counts, bpack,
                                               TB, gb, h1);
  // step 2: h1 -> out
  fused_msg_gru<<<kBlocks32, 256, 0, stream>>>(h1, ell, counts, bpack,
                                               TB, gb, out);
}

// Round 10
// 412.182 us; speedup vs baseline: 1.6746x; 1.6746x over previous
//
#include <hip/hip_runtime.h>
#include <stdint.h>

namespace {
constexpr int kNodes = 50000;
constexpr int kEdges = 800000;
constexpr int kHid   = 128;
constexpr int kCap   = 64;                      // ELL row capacity (λ=16)
constexpr int kBlocks16 = kNodes / 16;          // 3125 (EXACT, no tail)
constexpr int kFillBlocks = kEdges / 256;       // 3125
constexpr int kPackBlocks = 448;
constexpr int kConvBlocks = (kNodes * kHid / 2) / 256;  // 12500

// workspace layout (bytes) — ROUND-18 (r9 defensive rewrite)
constexpr size_t oCounts = 0;                   // 200704 (memset region)
constexpr size_t oBpack  = 200704;              // 655360
constexpr size_t oEll    = 856064;              // 12800000
constexpr size_t oH16a   = 13656064;            // 12800000 (bf16 h, step-1 gather table)
constexpr size_t oH16b   = 26456064;            // 12800000 (bf16 h1, step-2 gather table)
constexpr size_t oH1     = 39256064;            // 25600000 (fp32 h1)
constexpr size_t kWsNeeded = oH1 + 25600000;    // 64,856,064

// Bpack sub-offsets: Khi/Klo/Rhi/Rlo = r8-verified gru tables (swz_pi K rows);
// Whi/Wlo = r8-verified S-path W2 pack (K=512, N=128).
constexpr size_t bKhi = 0,      bKlo = 98304,  bRhi = 196608,
                 bRlo = 294912, bWhi = 393216, bWlo = 524288;
}

typedef __attribute__((ext_vector_type(8))) short short8;
typedef __attribute__((ext_vector_type(4))) float f32x4;

union ABFrag { short8 v; uint16_t u[8]; uint4 q; };

__device__ __forceinline__ uint16_t f2bf(float x) {
  uint32_t u = __float_as_uint(x);
  return (uint16_t)((u + 0x7FFFu + ((u >> 16) & 1u)) >> 16);
}
__device__ __forceinline__ float bf2f(uint16_t h) {
  return __uint_as_float(((uint32_t)h) << 16);
}

__device__ __forceinline__ float fast_rcp(float x) {
#if __has_builtin(__builtin_amdgcn_rcpf)
  return __builtin_amdgcn_rcpf(x);
#else
  return 1.f / x;
#endif
}
__device__ __forceinline__ float fast_exp2(float x) {
#if __has_builtin(__builtin_amdgcn_exp2f)
  return __builtin_amdgcn_exp2f(x);
#else
  return exp2f(x);
#endif
}
__device__ __forceinline__ float sigf(float x) {
  return fast_rcp(1.f + fast_exp2(-1.4426950408889634f * x));
}
__device__ __forceinline__ float tanh_fast(float x) {
  x = fminf(fmaxf(x, -10.f), 10.f);
  const float t = fast_exp2(2.8853900817779268f * x);  // e^(2x)
  return (t - 1.f) * fast_rcp(t + 1.f);
}

// msg k-position swizzle (r8-verified): position p holds original col pi(p).
__device__ __forceinline__ int swz_pi(int p) {
  return (p & 64) | ((p & 3) << 4) | ((p >> 2) & 15);
}

// ---------------- FUSED prep: ELL fill + B-pack + states->bf16 convert ------
__global__ __launch_bounds__(256) void pack_fill_conv_kernel(
    const int* __restrict__ edges, int* __restrict__ cnt,
    unsigned* __restrict__ ell,
    const float* __restrict__ K, const float* __restrict__ R,
    const float* __restrict__ W, uint16_t* __restrict__ bp,
    const float* __restrict__ states, uint32_t* __restrict__ h16a) {
  if (blockIdx.x < kFillBlocks) {
    const int e = blockIdx.x * 256 + threadIdx.x;
    if (e < kEdges) {
      const int et  = edges[e * 3 + 0];
      const int src = edges[e * 3 + 1];
      const int tgt = edges[e * 3 + 2];
      const int pos = atomicAdd(&cnt[tgt], 1);
      if (pos < kCap) ell[(size_t)tgt * kCap + pos] = (unsigned)(src * 4 + et);
    }
    return;
  }
  if (blockIdx.x < kFillBlocks + kPackBlocks) {
    const int idx = (blockIdx.x - kFillBlocks) * 256 + threadIdx.x;
    uint16_t* khi = bp + bKhi / 2;
    uint16_t* klo = bp + bKlo / 2;
    uint16_t* rhi = bp + bRhi / 2;
    uint16_t* rlo = bp + bRlo / 2;
    uint16_t* whi = bp + bWhi / 2;
    uint16_t* wlo = bp + bWlo / 2;
    if (idx < 128 * 384) {
      // K/R gru tables (r8-verified), K rows permuted by swz_pi
      const int k = idx / 384, c = idx % 384;
      const int ksrc = swz_pi(k);
      const int kt = k >> 5, quad = (k >> 3) & 3, j = k & 7;
      const int nt = c >> 4, ln = (c & 15) | (quad << 4);
      const size_t o = ((size_t)(kt * 24 + nt) * 64 + ln) * 8 + j;
      const float kv = K[ksrc * 384 + c];
      const float rv = R[k * 384 + c];
      const uint16_t kh = f2bf(kv), rh = f2bf(rv);
      khi[o] = kh; klo[o] = f2bf(kv - bf2f(kh));
      rhi[o] = rh; rlo[o] = f2bf(rv - bf2f(rh));
    } else if (idx < 128 * 384 + 128 * 512) {
      // W2 pack (r8-verified): kk = t*128+k in [0,512), col c in [0,128)
      const int i2 = idx - 128 * 384;
      const int kk = i2 >> 7;
      const int c  = i2 & 127;
      const int t = kk >> 7, k = kk & 127;
      const float wv = W[((size_t)t * 128 + k) * 128 + c];
      const int kt2 = kk >> 5, quad = (kk >> 3) & 3, j = kk & 7;
      const int nt = c >> 4, ln = (c & 15) | (quad << 4);
      const size_t o = ((size_t)(kt2 * 8 + nt) * 64 + ln) * 8 + j;
      const uint16_t wh = f2bf(wv);
      whi[o] = wh; wlo[o] = f2bf(wv - bf2f(wh));
    }
    return;
  }
  // ---- convert states -> bf16 pairs (lo halfword = even col)
  const int idx = (blockIdx.x - kFillBlocks - kPackBlocks) * 256 + threadIdx.x;
  if (idx < kNodes * kHid / 2) {
    const float2 s = ((const float2*)states)[idx];
    h16a[idx] = (uint32_t)f2bf(s.x) | ((uint32_t)f2bf(s.y) << 16);
  }
}

// ---------------- FUSED gather-S + S@W2 + GRU (ROUND-18 = r9, branch-free) --
// 16-node blocks (3125, exact). P1: 1 wave per node stream (4 streams/block,
// 8-deep ILP) gathers per-type sums from bf16 h16 (12.8MB table; 256B/edge)
// into LDS S[16][260]u32 (bf16 pairs, A-frag row-major, conflict-free).
// P2: msg = S @ W2 + D·TB (2-term split: S is bf16 so al=0; W hi+lo fully
// compensated). P3: r14 gru, mh from LDS msgT, hh direct from h16 (identical
// bits to f2bf(hin)), hp from fp32 hin. Epilogue ALWAYS writes h16out
// (step 2 targets a dead scratch buffer — the only r9 construct never
// previously exercised was the nullptr-guarded store; removed).
// No in-place hazard: hin != hout always (step1 states->h1, step2 h1->out).
__global__ __launch_bounds__(256, 2) void fused_msg_gru(
    const float* __restrict__ hin,      // [N][128] fp32 (states or h1)
    const uint32_t* __restrict__ h16,   // [N][64] bf16-pairs of hin
    const unsigned* __restrict__ ell,
    const int* __restrict__ counts,
    const uint16_t* __restrict__ bp,
    const float* __restrict__ TB,       // [4][128]
    const float* __restrict__ gb,       // [2][384]
    float* __restrict__ hout,           // [N][128] fp32 (!= hin)
    uint16_t* __restrict__ h16out) {    // bf16 copy of hout (always valid)
  __shared__ __align__(16) uint32_t S32[16 * 260];  // [node][260] (256 used)
  __shared__ int D[16][4];
  const int tid = threadIdx.x;
  const int w = tid >> 6;
  const int lane = tid & 63;
  const int node0 = blockIdx.x * 16;

  // ---- phase 1: gather. wave w handles nodes w*4..w*4+3; lane = k-pair.
  for (int i = 0; i < 4; ++i) {
    const int nl = w * 4 + i;
    const int v = node0 + nl;
    const int cnt = min(counts[v], kCap);
    const unsigned* __restrict__ row = ell + (size_t)v * kCap;
    float a0x = 0.f, a0y = 0.f, a1x = 0.f, a1y = 0.f;
    float a2x = 0.f, a2y = 0.f, a3x = 0.f, a3y = 0.f;
    int d0 = 0, d1 = 0, d2 = 0, d3 = 0;
    int e = 0;
    for (; e + 8 <= cnt; e += 8) {
      unsigned p[8]; uint32_t u[8];
#pragma unroll
      for (int q = 0; q < 8; ++q) p[q] = row[e + q];
#pragma unroll
      for (int q = 0; q < 8; ++q) u[q] = h16[(size_t)(p[q] >> 2) * 64 + lane];
#pragma unroll
      for (int q = 0; q < 8; ++q) {
        const float lo = __uint_as_float(u[q] << 16);
        const float hi = __uint_as_float(u[q] & 0xFFFF0000u);
        const int t = (int)(p[q] & 3u);
        a0x += (t == 0) ? lo : 0.f; a0y += (t == 0) ? hi : 0.f;
        a1x += (t == 1) ? lo : 0.f; a1y += (t == 1) ? hi : 0.f;
        a2x += (t == 2) ? lo : 0.f; a2y += (t == 2) ? hi : 0.f;
        a3x += (t == 3) ? lo : 0.f; a3y += (t == 3) ? hi : 0.f;
        d0 += (t == 0); d1 += (t == 1); d2 += (t == 2); d3 += (t == 3);
      }
    }
    for (; e < cnt; ++e) {
      const unsigned p = row[e];
      const uint32_t u = h16[(size_t)(p >> 2) * 64 + lane];
      const float lo = __uint_as_float(u << 16);
      const float hi = __uint_as_float(u & 0xFFFF0000u);
      const int t = (int)(p & 3u);
      a0x += (t == 0) ? lo : 0.f; a0y += (t == 0) ? hi : 0.f;
      a1x += (t == 1) ? lo : 0.f; a1y += (t == 1) ? hi : 0.f;
      a2x += (t == 2) ? lo : 0.f; a2y += (t == 2) ? hi : 0.f;
      a3x += (t == 3) ? lo : 0.f; a3y += (t == 3) ? hi : 0.f;
      d0 += (t == 0); d1 += (t == 1); d2 += (t == 2); d3 += (t == 3);
    }
    // S row nl: k = t*128 + lane*2 (+1). conflict-free (lane = consecutive bank)
    S32[nl * 260 + 0 * 64 + lane] = (uint32_t)f2bf(a0x) | ((uint32_t)f2bf(a0y) << 16);
    S32[nl * 260 + 1 * 64 + lane] = (uint32_t)f2bf(a1x) | ((uint32_t)f2bf(a1y) << 16);
    S32[nl * 260 + 2 * 64 + lane] = (uint32_t)f2bf(a2x) | ((uint32_t)f2bf(a2y) << 16);
    S32[nl * 260 + 3 * 64 + lane] = (uint32_t)f2bf(a3x) | ((uint32_t)f2bf(a3y) << 16);
    if (lane == 0) { D[nl][0] = d0; D[nl][1] = d1; D[nl][2] = d2; D[nl][3] = d3; }
  }
  __syncthreads();

  // ---- phase 2: msg = S @ W2 (M=16, N=128, K=512), 2-term split
  const int col16 = lane & 15, quad = lane >> 4;
  const uint4* __restrict__ Whi = (const uint4*)(bp + bWhi / 2);
  const uint4* __restrict__ Wlo = (const uint4*)(bp + bWlo / 2);

  f32x4 acc[2];
  acc[0] = (f32x4){0.f, 0.f, 0.f, 0.f};
  acc[1] = acc[0];

#pragma unroll
  for (int kt2 = 0; kt2 < 16; ++kt2) {
    ABFrag a;
    a.q = *(const uint4*)&S32[col16 * 260 + kt2 * 16 + quad * 4];
    ABFrag bh[2], bl[2];
#pragma unroll
    for (int lnt = 0; lnt < 2; ++lnt) {
      const size_t o = (size_t)(kt2 * 8 + w * 2 + lnt) * 64 + lane;
      bh[lnt].q = Whi[o]; bl[lnt].q = Wlo[o];
    }
#pragma unroll
    for (int lnt = 0; lnt < 2; ++lnt) {
      f32x4 c = acc[lnt];
      c = __builtin_amdgcn_mfma_f32_16x16x32_bf16(a.v, bh[lnt].v, c, 0, 0, 0);
      c = __builtin_amdgcn_mfma_f32_16x16x32_bf16(a.v, bl[lnt].v, c, 0, 0, 0);
      acc[lnt] = c;
    }
  }
  __syncthreads();   // S dead; overlay msgT

  // epilogue (r8-verified formulas, m=0): bias + f2bf -> swizzled msgT
  uint16_t* msgT16 = (uint16_t*)S32;
#pragma unroll
  for (int lnt = 0; lnt < 2; ++lnt) {
    const int c = (w * 2 + lnt) * 16 + col16;
    const float tb0 = TB[c], tb1 = TB[128 + c], tb2 = TB[256 + c],
                tb3 = TB[384 + c];
    const int p = ((c >> 6) << 6) | (col16 << 2) | ((c >> 4) & 3);
    const int kt = p >> 5, hi3 = (p >> 3) & 3, jq = p & 7;
#pragma unroll
    for (int r = 0; r < 4; ++r) {
      const int n16 = quad * 4 + r;
      const float bias = (float)D[n16][0] * tb0 + (float)D[n16][1] * tb1 +
                         (float)D[n16][2] * tb2 + (float)D[n16][3] * tb3;
      msgT16[((size_t)kt * 64 + hi3 * 16 + n16) * 8 + jq] =
          f2bf(acc[lnt][r] + bias);
    }
  }
  __syncthreads();

  // ---- phase 3: gru (r14 body, M=16 single m-tile; mh from LDS msgT,
  // hh direct from h16)
  const uint4* __restrict__ msgQ = (const uint4*)msgT16;
  const uint4* __restrict__ Khi = (const uint4*)(bp + bKhi / 2);
  const uint4* __restrict__ Klo = (const uint4*)(bp + bKlo / 2);
  const uint4* __restrict__ Rhi = (const uint4*)(bp + bRhi / 2);
  const uint4* __restrict__ Rlo = (const uint4*)(bp + bRlo / 2);

  f32x4 aZ[2], aR[2], aX[2], aH[2];
#pragma unroll
  for (int i = 0; i < 2; ++i) {
    aZ[i] = (f32x4){0.f, 0.f, 0.f, 0.f};
    aR[i] = aZ[i]; aX[i] = aZ[i]; aH[i] = aZ[i];
  }

  const uint32_t* __restrict__ h16row =
      h16 + (size_t)(node0 + col16) * 64 + quad * 4;

#pragma unroll
  for (int kt = 0; kt < 4; ++kt) {
    ABFrag BZ[2][4], BR[2][4], BH[2][4];  // [lnt][Khi,Klo,Rhi,Rlo]
#pragma unroll
    for (int lnt = 0; lnt < 2; ++lnt) {
      const int ntc = w * 2 + lnt;
      const size_t oz = (size_t)(kt * 24 + ntc) * 64 + lane;
      const size_t orr = (size_t)(kt * 24 + 8 + ntc) * 64 + lane;
      const size_t oh = (size_t)(kt * 24 + 16 + ntc) * 64 + lane;
      BZ[lnt][0].q = Khi[oz];  BZ[lnt][1].q = Klo[oz];
      BZ[lnt][2].q = Rhi[oz];  BZ[lnt][3].q = Rlo[oz];
      BR[lnt][0].q = Khi[orr]; BR[lnt][1].q = Klo[orr];
      BR[lnt][2].q = Rhi[orr]; BR[lnt][3].q = Rlo[orr];
      BH[lnt][0].q = Khi[oh];  BH[lnt][1].q = Klo[oh];
      BH[lnt][2].q = Rhi[oh];  BH[lnt][3].q = Rlo[oh];
    }
    ABFrag mh, hh;
    mh.q = msgQ[(size_t)kt * 64 + lane];
    hh.q = *(const uint4*)&h16row[kt * 16];
#pragma unroll
    for (int lnt = 0; lnt < 2; ++lnt) {
      f32x4 z = aZ[lnt];
      z = __builtin_amdgcn_mfma_f32_16x16x32_bf16(mh.v, BZ[lnt][0].v, z, 0, 0, 0);
      z = __builtin_amdgcn_mfma_f32_16x16x32_bf16(mh.v, BZ[lnt][1].v, z, 0, 0, 0);
      z = __builtin_amdgcn_mfma_f32_16x16x32_bf16(hh.v, BZ[lnt][2].v, z, 0, 0, 0);
      z = __builtin_amdgcn_mfma_f32_16x16x32_bf16(hh.v, BZ[lnt][3].v, z, 0, 0, 0);
      aZ[lnt] = z;
      f32x4 r = aR[lnt];
      r = __builtin_amdgcn_mfma_f32_16x16x32_bf16(mh.v, BR[lnt][0].v, r, 0, 0, 0);
      r = __builtin_amdgcn_mfma_f32_16x16x32_bf16(mh.v, BR[lnt][1].v, r, 0, 0, 0);
      r = __builtin_amdgcn_mfma_f32_16x16x32_bf16(hh.v, BR[lnt][2].v, r, 0, 0, 0);
      r = __builtin_amdgcn_mfma_f32_16x16x32_bf16(hh.v, BR[lnt][3].v, r, 0, 0, 0);
      aR[lnt] = r;
      f32x4 x = aX[lnt];
      x = __builtin_amdgcn_mfma_f32_16x16x32_bf16(mh.v, BH[lnt][0].v, x, 0, 0, 0);
      x = __builtin_amdgcn_mfma_f32_16x16x32_bf16(mh.v, BH[lnt][1].v, x, 0, 0, 0);
      aX[lnt] = x;
      f32x4 y = aH[lnt];
      y = __builtin_amdgcn_mfma_f32_16x16x32_bf16(hh.v, BH[lnt][2].v, y, 0, 0, 0);
      y = __builtin_amdgcn_mfma_f32_16x16x32_bf16(hh.v, BH[lnt][3].v, y, 0, 0, 0);
      aH[lnt] = y;
    }
  }

  // ---- gru epilogue (hout != hin: no hazard; h16out always valid)
#pragma unroll
  for (int lnt = 0; lnt < 2; ++lnt) {
    const int c = (w * 2 + lnt) * 16 + col16;
    const float bz = gb[c] + gb[384 + c];
    const float br = gb[128 + c] + gb[512 + c];
    const float bx = gb[256 + c];
    const float bh = gb[640 + c];
#pragma unroll
    for (int r = 0; r < 4; ++r) {
      const int node = node0 + quad * 4 + r;
      const float hp = hin[(size_t)node * kHid + c];
      const float z = sigf(aZ[lnt][r] + bz);
      const float rr = sigf(aR[lnt][r] + br);
      const float hh2 = tanh_fast(aX[lnt][r] + bx + rr * (aH[lnt][r] + bh));
      const float o = z * hp + (1.f - z) * hh2;
      hout[(size_t)node * kHid + c] = o;
      h16out[(size_t)node * kHid + c] = f2bf(o);
    }
  }
}

extern "C" void kernel_launch(void* const* d_in, const int* in_sizes, int n_in,
                              void* d_out, int out_size, void* d_ws, size_t ws_size,
                              hipStream_t stream) {
  const float* states = (const float*)d_in[0];
  const int*   edges  = (const int*)d_in[1];
  const float* W      = (const float*)d_in[2];
  const float* TB     = (const float*)d_in[3];
  const float* K      = (const float*)d_in[4];
  const float* R      = (const float*)d_in[5];
  const float* gb     = (const float*)d_in[6];
  float* out = (float*)d_out;

  if (ws_size < kWsNeeded) return;

  char* ws = (char*)d_ws;
  int*      counts = (int*)(ws + oCounts);
  uint16_t* bpack  = (uint16_t*)(ws + oBpack);
  unsigned* ell    = (unsigned*)(ws + oEll);
  uint32_t* h16a   = (uint32_t*)(ws + oH16a);
  uint32_t* h16b   = (uint32_t*)(ws + oH16b);
  float*    h1     = (float*)(ws + oH1);

  hipMemsetAsync(counts, 0, 200704, stream);
  pack_fill_conv_kernel<<<kFillBlocks + kPackBlocks + kConvBlocks, 256, 0,
                          stream>>>(edges, counts, ell, K, R, W, bpack,
                                    states, h16a);
  // step 1: states -> h1 (+ bf16 h16b for step-2 gather)
  fused_msg_gru<<<kBlocks16, 256, 0, stream>>>(
      states, h16a, ell, counts, bpack, TB, gb, h1, (uint16_t*)h16b);
  // step 2: h1 -> out (h16 output is a dead write into h16a — not read by
  // step 2; fully rewritten by the next replay's prep kernel)
  fused_msg_gru<<<kBlocks16, 256, 0, stream>>>(
      h1, h16b, ell, counts, bpack, TB, gb, out, (uint16_t*)h16a);
}

// Round 11
// 383.886 us; speedup vs baseline: 1.7980x; 1.0737x over previous
//
#include <hip/hip_runtime.h>
#include <stdint.h>

namespace {
constexpr int kNodes = 50000;
constexpr int kEdges = 800000;
constexpr int kHid   = 128;
constexpr int kCap   = 64;                      // ELL row capacity (λ=16)
constexpr int kBlocks16 = kNodes / 16;          // 3125 (EXACT, no tail)
constexpr int kFillBlocks = kEdges / 256;       // 3125
constexpr int kPackBlocks = 448;
constexpr int kConvBlocks = (kNodes * kHid / 2) / 256;  // 12500

// workspace layout (bytes) — ROUND-19 (= r18 layout)
constexpr size_t oCounts = 0;                   // 200704 (memset region)
constexpr size_t oBpack  = 200704;              // 655360
constexpr size_t oEll    = 856064;              // 12800000
constexpr size_t oH16a   = 13656064;            // 12800000 (bf16 h, step-1 gather table)
constexpr size_t oH16b   = 26456064;            // 12800000 (bf16 h1, step-2 gather table)
constexpr size_t oH1     = 39256064;            // 25600000 (fp32 h1)
constexpr size_t kWsNeeded = oH1 + 25600000;    // 64,856,064

// Bpack sub-offsets: Khi/Klo/Rhi/Rlo = r8-verified gru tables (swz_pi K rows);
// Whi/Wlo = r8-verified S-path W2 pack (K=512, N=128).
constexpr size_t bKhi = 0,      bKlo = 98304,  bRhi = 196608,
                 bRlo = 294912, bWhi = 393216, bWlo = 524288;
}

typedef __attribute__((ext_vector_type(8))) short short8;
typedef __attribute__((ext_vector_type(4))) float f32x4;

union ABFrag { short8 v; uint16_t u[8]; uint4 q; };

__device__ __forceinline__ uint16_t f2bf(float x) {
  uint32_t u = __float_as_uint(x);
  return (uint16_t)((u + 0x7FFFu + ((u >> 16) & 1u)) >> 16);
}
__device__ __forceinline__ float bf2f(uint16_t h) {
  return __uint_as_float(((uint32_t)h) << 16);
}

__device__ __forceinline__ float fast_rcp(float x) {
#if __has_builtin(__builtin_amdgcn_rcpf)
  return __builtin_amdgcn_rcpf(x);
#else
  return 1.f / x;
#endif
}
__device__ __forceinline__ float fast_exp2(float x) {
#if __has_builtin(__builtin_amdgcn_exp2f)
  return __builtin_amdgcn_exp2f(x);
#else
  return exp2f(x);
#endif
}
__device__ __forceinline__ float sigf(float x) {
  return fast_rcp(1.f + fast_exp2(-1.4426950408889634f * x));
}
__device__ __forceinline__ float tanh_fast(float x) {
  x = fminf(fmaxf(x, -10.f), 10.f);
  const float t = fast_exp2(2.8853900817779268f * x);  // e^(2x)
  return (t - 1.f) * fast_rcp(t + 1.f);
}

// msg k-position swizzle (r8-verified): position p holds original col pi(p).
__device__ __forceinline__ int swz_pi(int p) {
  return (p & 64) | ((p & 3) << 4) | ((p >> 2) & 15);
}

// ---------------- FUSED prep: ELL fill + B-pack + states->bf16 convert ------
__global__ __launch_bounds__(256) void pack_fill_conv_kernel(
    const int* __restrict__ edges, int* __restrict__ cnt,
    unsigned* __restrict__ ell,
    const float* __restrict__ K, const float* __restrict__ R,
    const float* __restrict__ W, uint16_t* __restrict__ bp,
    const float* __restrict__ states, uint32_t* __restrict__ h16a) {
  if (blockIdx.x < kFillBlocks) {
    const int e = blockIdx.x * 256 + threadIdx.x;
    if (e < kEdges) {
      const int et  = edges[e * 3 + 0];
      const int src = edges[e * 3 + 1];
      const int tgt = edges[e * 3 + 2];
      const int pos = atomicAdd(&cnt[tgt], 1);
      if (pos < kCap) ell[(size_t)tgt * kCap + pos] = (unsigned)(src * 4 + et);
    }
    return;
  }
  if (blockIdx.x < kFillBlocks + kPackBlocks) {
    const int idx = (blockIdx.x - kFillBlocks) * 256 + threadIdx.x;
    uint16_t* khi = bp + bKhi / 2;
    uint16_t* klo = bp + bKlo / 2;
    uint16_t* rhi = bp + bRhi / 2;
    uint16_t* rlo = bp + bRlo / 2;
    uint16_t* whi = bp + bWhi / 2;
    uint16_t* wlo = bp + bWlo / 2;
    if (idx < 128 * 384) {
      // K/R gru tables (r8-verified), K rows permuted by swz_pi
      const int k = idx / 384, c = idx % 384;
      const int ksrc = swz_pi(k);
      const int kt = k >> 5, quad = (k >> 3) & 3, j = k & 7;
      const int nt = c >> 4, ln = (c & 15) | (quad << 4);
      const size_t o = ((size_t)(kt * 24 + nt) * 64 + ln) * 8 + j;
      const float kv = K[ksrc * 384 + c];
      const float rv = R[k * 384 + c];
      const uint16_t kh = f2bf(kv), rh = f2bf(rv);
      khi[o] = kh; klo[o] = f2bf(kv - bf2f(kh));
      rhi[o] = rh; rlo[o] = f2bf(rv - bf2f(rh));
    } else if (idx < 128 * 384 + 128 * 512) {
      // W2 pack (r8-verified): kk = t*128+k in [0,512), col c in [0,128)
      const int i2 = idx - 128 * 384;
      const int kk = i2 >> 7;
      const int c  = i2 & 127;
      const int t = kk >> 7, k = kk & 127;
      const float wv = W[((size_t)t * 128 + k) * 128 + c];
      const int kt2 = kk >> 5, quad = (kk >> 3) & 3, j = kk & 7;
      const int nt = c >> 4, ln = (c & 15) | (quad << 4);
      const size_t o = ((size_t)(kt2 * 8 + nt) * 64 + ln) * 8 + j;
      const uint16_t wh = f2bf(wv);
      whi[o] = wh; wlo[o] = f2bf(wv - bf2f(wh));
    }
    return;
  }
  // ---- convert states -> bf16 pairs (lo halfword = even col)
  const int idx = (blockIdx.x - kFillBlocks - kPackBlocks) * 256 + threadIdx.x;
  if (idx < kNodes * kHid / 2) {
    const float2 s = ((const float2*)states)[idx];
    h16a[idx] = (uint32_t)f2bf(s.x) | ((uint32_t)f2bf(s.y) << 16);
  }
}

// ---------------- FUSED gather-S + S@W2 + GRU (ROUND-19) ----------------
// = r18 (verified, 149us/dispatch) with ONE change: residency cap 2 -> 6
// blocks/CU. r10 counters: FETCH 106MB = 8 XCD x 12.8MB table (compulsory
// floor, model confirmed by r8's 194 = 8 x 25.6), but effective BW only
// 0.97 TB/s < 1.4 achievable and Occ 37% with VGPR=64/LDS=16.6KB at a
// launch_bounds(256,2) hard cap -> latency-bound gather with idle headroom.
// 6 blocks/CU: VGPR cap 85 (>64 used, no spill), LDS 101KB < 160KB.
__global__ __launch_bounds__(256, 6) void fused_msg_gru(
    const float* __restrict__ hin,      // [N][128] fp32 (states or h1)
    const uint32_t* __restrict__ h16,   // [N][64] bf16-pairs of hin
    const unsigned* __restrict__ ell,
    const int* __restrict__ counts,
    const uint16_t* __restrict__ bp,
    const float* __restrict__ TB,       // [4][128]
    const float* __restrict__ gb,       // [2][384]
    float* __restrict__ hout,           // [N][128] fp32 (!= hin)
    uint16_t* __restrict__ h16out) {    // bf16 copy of hout (always valid)
  __shared__ __align__(16) uint32_t S32[16 * 260];  // [node][260] (256 used)
  __shared__ int D[16][4];
  const int tid = threadIdx.x;
  const int w = tid >> 6;
  const int lane = tid & 63;
  const int node0 = blockIdx.x * 16;

  // ---- phase 1: gather. wave w handles nodes w*4..w*4+3; lane = k-pair.
  for (int i = 0; i < 4; ++i) {
    const int nl = w * 4 + i;
    const int v = node0 + nl;
    const int cnt = min(counts[v], kCap);
    const unsigned* __restrict__ row = ell + (size_t)v * kCap;
    float a0x = 0.f, a0y = 0.f, a1x = 0.f, a1y = 0.f;
    float a2x = 0.f, a2y = 0.f, a3x = 0.f, a3y = 0.f;
    int d0 = 0, d1 = 0, d2 = 0, d3 = 0;
    int e = 0;
    for (; e + 8 <= cnt; e += 8) {
      unsigned p[8]; uint32_t u[8];
#pragma unroll
      for (int q = 0; q < 8; ++q) p[q] = row[e + q];
#pragma unroll
      for (int q = 0; q < 8; ++q) u[q] = h16[(size_t)(p[q] >> 2) * 64 + lane];
#pragma unroll
      for (int q = 0; q < 8; ++q) {
        const float lo = __uint_as_float(u[q] << 16);
        const float hi = __uint_as_float(u[q] & 0xFFFF0000u);
        const int t = (int)(p[q] & 3u);
        a0x += (t == 0) ? lo : 0.f; a0y += (t == 0) ? hi : 0.f;
        a1x += (t == 1) ? lo : 0.f; a1y += (t == 1) ? hi : 0.f;
        a2x += (t == 2) ? lo : 0.f; a2y += (t == 2) ? hi : 0.f;
        a3x += (t == 3) ? lo : 0.f; a3y += (t == 3) ? hi : 0.f;
        d0 += (t == 0); d1 += (t == 1); d2 += (t == 2); d3 += (t == 3);
      }
    }
    for (; e < cnt; ++e) {
      const unsigned p = row[e];
      const uint32_t u = h16[(size_t)(p >> 2) * 64 + lane];
      const float lo = __uint_as_float(u << 16);
      const float hi = __uint_as_float(u & 0xFFFF0000u);
      const int t = (int)(p & 3u);
      a0x += (t == 0) ? lo : 0.f; a0y += (t == 0) ? hi : 0.f;
      a1x += (t == 1) ? lo : 0.f; a1y += (t == 1) ? hi : 0.f;
      a2x += (t == 2) ? lo : 0.f; a2y += (t == 2) ? hi : 0.f;
      a3x += (t == 3) ? lo : 0.f; a3y += (t == 3) ? hi : 0.f;
      d0 += (t == 0); d1 += (t == 1); d2 += (t == 2); d3 += (t == 3);
    }
    // S row nl: k = t*128 + lane*2 (+1). conflict-free (lane = consecutive bank)
    S32[nl * 260 + 0 * 64 + lane] = (uint32_t)f2bf(a0x) | ((uint32_t)f2bf(a0y) << 16);
    S32[nl * 260 + 1 * 64 + lane] = (uint32_t)f2bf(a1x) | ((uint32_t)f2bf(a1y) << 16);
    S32[nl * 260 + 2 * 64 + lane] = (uint32_t)f2bf(a2x) | ((uint32_t)f2bf(a2y) << 16);
    S32[nl * 260 + 3 * 64 + lane] = (uint32_t)f2bf(a3x) | ((uint32_t)f2bf(a3y) << 16);
    if (lane == 0) { D[nl][0] = d0; D[nl][1] = d1; D[nl][2] = d2; D[nl][3] = d3; }
  }
  __syncthreads();

  // ---- phase 2: msg = S @ W2 (M=16, N=128, K=512), 2-term split
  const int col16 = lane & 15, quad = lane >> 4;
  const uint4* __restrict__ Whi = (const uint4*)(bp + bWhi / 2);
  const uint4* __restrict__ Wlo = (const uint4*)(bp + bWlo / 2);

  f32x4 acc[2];
  acc[0] = (f32x4){0.f, 0.f, 0.f, 0.f};
  acc[1] = acc[0];

#pragma unroll
  for (int kt2 = 0; kt2 < 16; ++kt2) {
    ABFrag a;
    a.q = *(const uint4*)&S32[col16 * 260 + kt2 * 16 + quad * 4];
    ABFrag bh[2], bl[2];
#pragma unroll
    for (int lnt = 0; lnt < 2; ++lnt) {
      const size_t o = (size_t)(kt2 * 8 + w * 2 + lnt) * 64 + lane;
      bh[lnt].q = Whi[o]; bl[lnt].q = Wlo[o];
    }
#pragma unroll
    for (int lnt = 0; lnt < 2; ++lnt) {
      f32x4 c = acc[lnt];
      c = __builtin_amdgcn_mfma_f32_16x16x32_bf16(a.v, bh[lnt].v, c, 0, 0, 0);
      c = __builtin_amdgcn_mfma_f32_16x16x32_bf16(a.v, bl[lnt].v, c, 0, 0, 0);
      acc[lnt] = c;
    }
  }
  __syncthreads();   // S dead; overlay msgT

  // epilogue (r8-verified formulas, m=0): bias + f2bf -> swizzled msgT
  uint16_t* msgT16 = (uint16_t*)S32;
#pragma unroll
  for (int lnt = 0; lnt < 2; ++lnt) {
    const int c = (w * 2 + lnt) * 16 + col16;
    const float tb0 = TB[c], tb1 = TB[128 + c], tb2 = TB[256 + c],
                tb3 = TB[384 + c];
    const int p = ((c >> 6) << 6) | (col16 << 2) | ((c >> 4) & 3);
    const int kt = p >> 5, hi3 = (p >> 3) & 3, jq = p & 7;
#pragma unroll
    for (int r = 0; r < 4; ++r) {
      const int n16 = quad * 4 + r;
      const float bias = (float)D[n16][0] * tb0 + (float)D[n16][1] * tb1 +
                         (float)D[n16][2] * tb2 + (float)D[n16][3] * tb3;
      msgT16[((size_t)kt * 64 + hi3 * 16 + n16) * 8 + jq] =
          f2bf(acc[lnt][r] + bias);
    }
  }
  __syncthreads();

  // ---- phase 3: gru (r14 body, M=16 single m-tile; mh from LDS msgT,
  // hh direct from h16)
  const uint4* __restrict__ msgQ = (const uint4*)msgT16;
  const uint4* __restrict__ Khi = (const uint4*)(bp + bKhi / 2);
  const uint4* __restrict__ Klo = (const uint4*)(bp + bKlo / 2);
  const uint4* __restrict__ Rhi = (const uint4*)(bp + bRhi / 2);
  const uint4* __restrict__ Rlo = (const uint4*)(bp + bRlo / 2);

  f32x4 aZ[2], aR[2], aX[2], aH[2];
#pragma unroll
  for (int i = 0; i < 2; ++i) {
    aZ[i] = (f32x4){0.f, 0.f, 0.f, 0.f};
    aR[i] = aZ[i]; aX[i] = aZ[i]; aH[i] = aZ[i];
  }

  const uint32_t* __restrict__ h16row =
      h16 + (size_t)(node0 + col16) * 64 + quad * 4;

#pragma unroll
  for (int kt = 0; kt < 4; ++kt) {
    ABFrag BZ[2][4], BR[2][4], BH[2][4];  // [lnt][Khi,Klo,Rhi,Rlo]
#pragma unroll
    for (int lnt = 0; lnt < 2; ++lnt) {
      const int ntc = w * 2 + lnt;
      const size_t oz = (size_t)(kt * 24 + ntc) * 64 + lane;
      const size_t orr = (size_t)(kt * 24 + 8 + ntc) * 64 + lane;
      const size_t oh = (size_t)(kt * 24 + 16 + ntc) * 64 + lane;
      BZ[lnt][0].q = Khi[oz];  BZ[lnt][1].q = Klo[oz];
      BZ[lnt][2].q = Rhi[oz];  BZ[lnt][3].q = Rlo[oz];
      BR[lnt][0].q = Khi[orr]; BR[lnt][1].q = Klo[orr];
      BR[lnt][2].q = Rhi[orr]; BR[lnt][3].q = Rlo[orr];
      BH[lnt][0].q = Khi[oh];  BH[lnt][1].q = Klo[oh];
      BH[lnt][2].q = Rhi[oh];  BH[lnt][3].q = Rlo[oh];
    }
    ABFrag mh, hh;
    mh.q = msgQ[(size_t)kt * 64 + lane];
    hh.q = *(const uint4*)&h16row[kt * 16];
#pragma unroll
    for (int lnt = 0; lnt < 2; ++lnt) {
      f32x4 z = aZ[lnt];
      z = __builtin_amdgcn_mfma_f32_16x16x32_bf16(mh.v, BZ[lnt][0].v, z, 0, 0, 0);
      z = __builtin_amdgcn_mfma_f32_16x16x32_bf16(mh.v, BZ[lnt][1].v, z, 0, 0, 0);
      z = __builtin_amdgcn_mfma_f32_16x16x32_bf16(hh.v, BZ[lnt][2].v, z, 0, 0, 0);
      z = __builtin_amdgcn_mfma_f32_16x16x32_bf16(hh.v, BZ[lnt][3].v, z, 0, 0, 0);
      aZ[lnt] = z;
      f32x4 r = aR[lnt];
      r = __builtin_amdgcn_mfma_f32_16x16x32_bf16(mh.v, BR[lnt][0].v, r, 0, 0, 0);
      r = __builtin_amdgcn_mfma_f32_16x16x32_bf16(mh.v, BR[lnt][1].v, r, 0, 0, 0);
      r = __builtin_amdgcn_mfma_f32_16x16x32_bf16(hh.v, BR[lnt][2].v, r, 0, 0, 0);
      r = __builtin_amdgcn_mfma_f32_16x16x32_bf16(hh.v, BR[lnt][3].v, r, 0, 0, 0);
      aR[lnt] = r;
      f32x4 x = aX[lnt];
      x = __builtin_amdgcn_mfma_f32_16x16x32_bf16(mh.v, BH[lnt][0].v, x, 0, 0, 0);
      x = __builtin_amdgcn_mfma_f32_16x16x32_bf16(mh.v, BH[lnt][1].v, x, 0, 0, 0);
      aX[lnt] = x;
      f32x4 y = aH[lnt];
      y = __builtin_amdgcn_mfma_f32_16x16x32_bf16(hh.v, BH[lnt][2].v, y, 0, 0, 0);
      y = __builtin_amdgcn_mfma_f32_16x16x32_bf16(hh.v, BH[lnt][3].v, y, 0, 0, 0);
      aH[lnt] = y;
    }
  }

  // ---- gru epilogue (hout != hin: no hazard; h16out always valid)
#pragma unroll
  for (int lnt = 0; lnt < 2; ++lnt) {
    const int c = (w * 2 + lnt) * 16 + col16;
    const float bz = gb[c] + gb[384 + c];
    const float br = gb[128 + c] + gb[512 + c];
    const float bx = gb[256 + c];
    const float bh = gb[640 + c];
#pragma unroll
    for (int r = 0; r < 4; ++r) {
      const int node = node0 + quad * 4 + r;
      const float hp = hin[(size_t)node * kHid + c];
      const float z = sigf(aZ[lnt][r] + bz);
      const float rr = sigf(aR[lnt][r] + br);
      const float hh2 = tanh_fast(aX[lnt][r] + bx + rr * (aH[lnt][r] + bh));
      const float o = z * hp + (1.f - z) * hh2;
      hout[(size_t)node * kHid + c] = o;
      h16out[(size_t)node * kHid + c] = f2bf(o);
    }
  }
}

extern "C" void kernel_launch(void* const* d_in, const int* in_sizes, int n_in,
                              void* d_out, int out_size, void* d_ws, size_t ws_size,
                              hipStream_t stream) {
  const float* states = (const float*)d_in[0];
  const int*   edges  = (const int*)d_in[1];
  const float* W      = (const float*)d_in[2];
  const float* TB     = (const float*)d_in[3];
  const float* K      = (const float*)d_in[4];
  const float* R      = (const float*)d_in[5];
  const float* gb     = (const float*)d_in[6];
  float* out = (float*)d_out;

  if (ws_size < kWsNeeded) return;

  char* ws = (char*)d_ws;
  int*      counts = (int*)(ws + oCounts);
  uint16_t* bpack  = (uint16_t*)(ws + oBpack);
  unsigned* ell    = (unsigned*)(ws + oEll);
  uint32_t* h16a   = (uint32_t*)(ws + oH16a);
  uint32_t* h16b   = (uint32_t*)(ws + oH16b);
  float*    h1     = (float*)(ws + oH1);

  hipMemsetAsync(counts, 0, 200704, stream);
  pack_fill_conv_kernel<<<kFillBlocks + kPackBlocks + kConvBlocks, 256, 0,
                          stream>>>(edges, counts, ell, K, R, W, bpack,
                                    states, h16a);
  // step 1: states -> h1 (+ bf16 h16b for step-2 gather)
  fused_msg_gru<<<kBlocks16, 256, 0, stream>>>(
      states, h16a, ell, counts, bpack, TB, gb, h1, (uint16_t*)h16b);
  // step 2: h1 -> out (h16 output is a dead write into h16a — not read by
  // step 2; fully rewritten by the next replay's prep kernel)
  fused_msg_gru<<<kBlocks16, 256, 0, stream>>>(
      h1, h16b, ell, counts, bpack, TB, gb, out, (uint16_t*)h16a);
}